// Round 13
// baseline (304.395 us; speedup 1.0000x reference)
//
#include <hip/hip_runtime.h>
#include <math.h>
#include <stddef.h>

#define BB 4
#define LL 1024
#define DM 512
#define ED 1024
#define NST 16
#define DTR 32
#define XDBC 64
#define BL (BB*LL)   // 4096
#define CS 16        // scan chunk length
#define NC 64        // chunks per sequence (LL/CS)
#define MT 16        // k_mid time-rows per block

typedef __attribute__((ext_vector_type(8))) short bf16x8;
typedef __attribute__((ext_vector_type(4))) float f32x4;
typedef unsigned short ushort_t;

__device__ __forceinline__ float silu_f(float x) { return x / (1.f + __expf(-x)); }

__device__ __forceinline__ ushort_t f2b(float f) {
    unsigned int u = __float_as_uint(f);
    unsigned int r = (u + 0x7FFFu + ((u >> 16) & 1u)) >> 16;
    return (ushort_t)r;
}
__device__ __forceinline__ float b2f(ushort_t v) {
    return __uint_as_float(((unsigned int)v) << 16);
}
__device__ __forceinline__ ushort_t f2h(float f) {
    _Float16 h = (_Float16)f;
    return *(ushort_t*)&h;
}
__device__ __forceinline__ float h2f(ushort_t v) {
    _Float16 h = *(_Float16*)&v;
    return (float)h;
}

__device__ __forceinline__ void gload16(const ushort_t* g, ushort_t* l) {
    __builtin_amdgcn_global_load_lds(
        (const __attribute__((address_space(1))) unsigned int*)g,
        (__attribute__((address_space(3))) unsigned int*)l, 16, 0, 0);
}

// ---------------- init: embedding + both weight cvt in one dispatch
__global__ void k_init(const float* __restrict__ x, const float* __restrict__ embW,
                       const float* __restrict__ embB, float* __restrict__ h,
                       const float* __restrict__ ipW, const float* __restrict__ opW,
                       ushort_t* __restrict__ wip, ushort_t* __restrict__ wop,
                       int nEmb, int n1, int n2) {
    int i = blockIdx.x * 256 + threadIdx.x;
    if (i < nEmb) {
        int d = i % DM, r = i / DM;
        h[i] = x[r * 2 + 0] * embW[d * 2 + 0] + x[r * 2 + 1] * embW[d * 2 + 1] + embB[d];
        return;
    }
    i -= nEmb;
    const float* src; ushort_t* dst; int q;
    if (i < n1) { src = ipW; dst = wip; q = i; }
    else if (i < n1 + n2) { src = opW; dst = wop; q = i - n1; }
    else return;
    float4 v = *(const float4*)(src + (size_t)q * 4);
    ushort_t o[4] = {f2b(v.x), f2b(v.y), f2b(v.z), f2b(v.w)};
    *(uint2*)(dst + (size_t)q * 4) = *(uint2*)o;
}

// ---------------- rmsnorm over rows of 512
template <int BF16OUT>
__global__ __launch_bounds__(256) void k_rmsnorm(const float* __restrict__ in,
                                                 const float* __restrict__ w,
                                                 void* __restrict__ outp) {
    int m = blockIdx.x;
    int tid = threadIdx.x;
    const float* row = in + (size_t)m * DM;
    float2 v = *(const float2*)(row + tid * 2);
    float ss = v.x * v.x + v.y * v.y;
    #pragma unroll
    for (int o = 32; o > 0; o >>= 1) ss += __shfl_down(ss, o, 64);
    __shared__ float red[4];
    int wid = tid >> 6;
    if ((tid & 63) == 0) red[wid] = ss;
    __syncthreads();
    float tot = red[0] + red[1] + red[2] + red[3];
    float rs = rsqrtf(tot * (1.f / DM) + 1e-5f);
    float2 wv = *(const float2*)(w + tid * 2);
    float ox = v.x * rs * wv.x;
    float oy = v.y * rs * wv.y;
    if (BF16OUT) {
        ushort_t o[2] = {f2b(ox), f2b(oy)};
        *(unsigned int*)((ushort_t*)outp + (size_t)m * DM + tid * 2) = *(unsigned int*)o;
    } else {
        *(float2*)((float*)outp + (size_t)m * DM + tid * 2) = make_float2(ox, oy);
    }
}

// ---------------- bf16 MFMA GEMM (round-12 structure, unchanged)
template <int ADDRES, int BF16OUT, int NT>
__global__ __launch_bounds__(256) void k_bgemm(const ushort_t* __restrict__ A,
                                               const ushort_t* __restrict__ W,
                                               const float* __restrict__ Res,
                                               void* __restrict__ C,
                                               int M, int N, int K, int lda, int ldc) {
    __shared__ ushort_t As[128 * 32];
    __shared__ ushort_t Bs[NT * 32];
    constexpr int NFJ = NT / 32;
    int tid = threadIdx.x;
    int bm = blockIdx.y * 128, bn = blockIdx.x * NT;
    int wave = tid >> 6, lane = tid & 63;
    int wr = wave >> 1, wc = wave & 1;
    int lr = lane & 15;
    int kc = lane >> 4;
    f32x4 acc[4][NFJ];
    #pragma unroll
    for (int i = 0; i < 4; ++i)
        #pragma unroll
        for (int j = 0; j < NFJ; ++j) acc[i][j] = (f32x4){0.f, 0.f, 0.f, 0.f};

    for (int k0 = 0; k0 < K; k0 += 32) {
        __syncthreads();
        #pragma unroll
        for (int ii = 0; ii < 2; ++ii) {
            int g = wave * 128 + ii * 64 + lane;
            int row = g >> 2;
            int c = (g & 3) ^ ((g >> 3) & 3);
            gload16(A + (size_t)(bm + row) * lda + k0 + c * 8,
                    As + (size_t)(wave * 128 + ii * 64) * 8);
        }
        #pragma unroll
        for (int ii = 0; ii < NFJ / 2; ++ii) {
            int g = wave * (NFJ / 2) * 64 + ii * 64 + lane;
            int row = g >> 2;
            int c = (g & 3) ^ ((g >> 3) & 3);
            gload16(W + (size_t)(bn + row) * K + k0 + c * 8,
                    Bs + (size_t)(wave * (NFJ / 2) * 64 + ii * 64) * 8);
        }
        __syncthreads();
        bf16x8 af[4], bfr[NFJ];
        #pragma unroll
        for (int i = 0; i < 4; ++i) {
            int ra = wr * 64 + i * 16 + lr;
            int ca = kc ^ ((ra >> 1) & 3);
            af[i] = *(const bf16x8*)(As + ra * 32 + ca * 8);
        }
        #pragma unroll
        for (int j = 0; j < NFJ; ++j) {
            int rb = wc * (NT / 2) + j * 16 + lr;
            int cb = kc ^ ((rb >> 1) & 3);
            bfr[j] = *(const bf16x8*)(Bs + rb * 32 + cb * 8);
        }
        #pragma unroll
        for (int i = 0; i < 4; ++i)
            #pragma unroll
            for (int j = 0; j < NFJ; ++j)
                acc[i][j] = __builtin_amdgcn_mfma_f32_16x16x32_bf16(af[i], bfr[j], acc[i][j], 0, 0, 0);
    }
    int crow0 = bm + wr * 64 + (lane >> 4) * 4;
    #pragma unroll
    for (int i = 0; i < 4; ++i)
        #pragma unroll
        for (int j = 0; j < NFJ; ++j)
            #pragma unroll
            for (int r = 0; r < 4; ++r) {
                size_t off = (size_t)(crow0 + i * 16 + r) * ldc + bn + wc * (NT / 2) + j * 16 + lr;
                float v = acc[i][j][r];
                if (ADDRES) v += Res[off];
                if (BF16OUT) ((ushort_t*)C)[off] = f2b(v);
                else         ((float*)C)[off] = v;
            }
}

// ---------------- fused mid: conv+silu -> xproj (full-K) -> delta(softplus)
// One block = MT=16 consecutive time-rows. 512 threads.
__global__ __launch_bounds__(512) void k_mid(const ushort_t* __restrict__ xzb,
                                             const float* __restrict__ cw,
                                             const float* __restrict__ cb,
                                             const float* __restrict__ xpW,
                                             const float* __restrict__ dtW,
                                             const float* __restrict__ dtb,
                                             ushort_t* __restrict__ ub,
                                             float* __restrict__ xdb,
                                             ushort_t* __restrict__ dyh) {
    __shared__ ushort_t Ut[MT][1032];    // bf16 u tile (+8 pad)
    __shared__ float Wt[64][68];         // transposed xpW chunk [k][n]
    __shared__ float Xs[MT][68];         // xdb tile
    __shared__ float Xs2[MT][68];        // k-split partial
    int tid = threadIdx.x;
    int bm = blockIdx.x * MT;

    // ---- phase 1: u = silu(conv(xz)+cb); write LDS + global ub
    {
        int e0 = (tid & 255) * 4;
        int th = (tid >> 8) * 8;
        float cw4[4][4], cb4[4];
        #pragma unroll
        for (int i = 0; i < 4; ++i) {
            float4 w = *(const float4*)(cw + (size_t)(e0 + i) * 4);
            cw4[i][0] = w.x; cw4[i][1] = w.y; cw4[i][2] = w.z; cw4[i][3] = w.w;
        }
        float4 cbv = *(const float4*)(cb + e0);
        cb4[0] = cbv.x; cb4[1] = cbv.y; cb4[2] = cbv.z; cb4[3] = cbv.w;
        #pragma unroll
        for (int i = 0; i < 8; ++i) {
            int t = th + i;
            int row = bm + t;
            int tloc = row & (LL - 1);
            const ushort_t* xrow = xzb + (size_t)row * 2048 + e0;
            uint2 z2 = make_uint2(0, 0);
            uint2 v3 = *(const uint2*)xrow;
            uint2 v2 = (tloc >= 1) ? *(const uint2*)(xrow - 2048) : z2;
            uint2 v1 = (tloc >= 2) ? *(const uint2*)(xrow - 4096) : z2;
            uint2 v0 = (tloc >= 3) ? *(const uint2*)(xrow - 6144) : z2;
            const ushort_t* p0 = (const ushort_t*)&v0;
            const ushort_t* p1 = (const ushort_t*)&v1;
            const ushort_t* p2 = (const ushort_t*)&v2;
            const ushort_t* p3 = (const ushort_t*)&v3;
            ushort_t ures[4];
            #pragma unroll
            for (int e = 0; e < 4; ++e) {
                float a = cb4[e] + b2f(p0[e]) * cw4[e][0] + b2f(p1[e]) * cw4[e][1]
                                 + b2f(p2[e]) * cw4[e][2] + b2f(p3[e]) * cw4[e][3];
                ures[e] = f2b(silu_f(a));
            }
            *(uint2*)(&Ut[t][e0]) = *(uint2*)ures;
            *(uint2*)(ub + (size_t)row * ED + e0) = *(uint2*)ures;
        }
    }
    __syncthreads();

    // ---- phase 2: xdb[16][64] = u . xpW^T, K=1024, k-split 2
    {
        int n0 = (tid & 15) * 4;
        int tg = tid >> 4;
        int t = tg & 15;
        int ks = tg >> 4;                 // 0 or 1
        f32x4 acc = (f32x4){0.f, 0.f, 0.f, 0.f};
        int wn = tid >> 3, wq = tid & 7;  // Wtile loader mapping
        for (int kcn = 0; kcn < 16; ++kcn) {
            __syncthreads();
            {
                const float4* wp = (const float4*)(xpW + (size_t)wn * ED + kcn * 64 + wq * 8);
                float4 wa = wp[0], wb = wp[1];
                // transpose into Wt[k][n]
                float wv[8] = {wa.x, wa.y, wa.z, wa.w, wb.x, wb.y, wb.z, wb.w};
                #pragma unroll
                for (int r = 0; r < 8; ++r) Wt[wq * 8 + r][wn] = wv[r];
            }
            __syncthreads();
            const ushort_t* urow = &Ut[t][kcn * 64 + ks * 32];
            #pragma unroll 8
            for (int j = 0; j < 32; ++j) {
                float uu = b2f(urow[j]);
                float4 wv = *(const float4*)&Wt[ks * 32 + j][n0];
                acc.x += uu * wv.x; acc.y += uu * wv.y;
                acc.z += uu * wv.z; acc.w += uu * wv.w;
            }
        }
        if (ks == 1) *(f32x4*)&Xs2[t][n0] = acc;
        __syncthreads();
        if (ks == 0) {
            f32x4 o = *(const f32x4*)&Xs2[t][n0];
            o.x += acc.x; o.y += acc.y; o.z += acc.z; o.w += acc.w;
            *(f32x4*)&Xs[t][n0] = o;
            *(float4*)(xdb + (size_t)(bm + t) * XDBC + n0) = make_float4(o.x, o.y, o.z, o.w);
        }
    }
    __syncthreads();

    // ---- phase 3: delta = softplus(Xs[t][0:32] . dtW[e] + dtb[e]) -> fp16
    #pragma unroll
    for (int eh = 0; eh < 2; ++eh) {
        int e = eh * 512 + tid;
        float w[32];
        const float4* wp = (const float4*)(dtW + (size_t)e * DTR);
        #pragma unroll
        for (int q = 0; q < 8; ++q) {
            float4 v = wp[q];
            w[q * 4 + 0] = v.x; w[q * 4 + 1] = v.y;
            w[q * 4 + 2] = v.z; w[q * 4 + 3] = v.w;
        }
        float bias = dtb[e];
        #pragma unroll
        for (int t = 0; t < MT; ++t) {
            float accv = bias;
            #pragma unroll
            for (int q = 0; q < 8; ++q) {
                float4 d = *(const float4*)&Xs[t][q * 4];
                accv += d.x * w[q * 4 + 0] + d.y * w[q * 4 + 1] +
                        d.z * w[q * 4 + 2] + d.w * w[q * 4 + 3];
            }
            float dv = (accv > 20.f) ? accv : __logf(1.f + __expf(accv));
            dyh[(size_t)(bm + t) * ED + e] = f2h(dv);
        }
    }
}

// ================ chunked selective scan (CS=16, NC=64) ================
__global__ __launch_bounds__(256) void k_scan1(const ushort_t* __restrict__ dyh,
                                               const ushort_t* __restrict__ u,
                                               const float* __restrict__ xdb,
                                               const float* __restrict__ A_log,
                                               float* __restrict__ P,
                                               float* __restrict__ S) {
    int tid = threadIdx.x;
    int e = ((blockIdx.x & 3) << 8) + tid;
    int c = (blockIdx.x >> 2) & (NC - 1);
    int b = blockIdx.x >> 8;
    float Ac[16];
    const float4* ap = (const float4*)(A_log + (size_t)e * NST);
    #pragma unroll
    for (int q = 0; q < 4; ++q) {
        float4 a = ap[q];
        Ac[q * 4 + 0] = -__expf(a.x); Ac[q * 4 + 1] = -__expf(a.y);
        Ac[q * 4 + 2] = -__expf(a.z); Ac[q * 4 + 3] = -__expf(a.w);
    }
    float h[16] = {};
    float s = 0.f;
    const ushort_t* dp = dyh + ((size_t)b * LL + c * CS) * ED + e;
    const ushort_t* up = u + ((size_t)b * LL + c * CS) * ED + e;
    const float* xp = xdb + ((size_t)b * LL + c * CS) * XDBC;
    for (int tt = 0; tt < CS; ++tt) {
        float dv = h2f(dp[(size_t)tt * ED]);
        float uv = b2f(up[(size_t)tt * ED]);
        s += dv;
        float du = dv * uv;
        const float4* bp = (const float4*)(xp + tt * XDBC + DTR);
        #pragma unroll
        for (int q = 0; q < 4; ++q) {
            float4 bv = bp[q];
            h[q * 4 + 0] = __expf(dv * Ac[q * 4 + 0]) * h[q * 4 + 0] + du * bv.x;
            h[q * 4 + 1] = __expf(dv * Ac[q * 4 + 1]) * h[q * 4 + 1] + du * bv.y;
            h[q * 4 + 2] = __expf(dv * Ac[q * 4 + 2]) * h[q * 4 + 2] + du * bv.z;
            h[q * 4 + 3] = __expf(dv * Ac[q * 4 + 3]) * h[q * 4 + 3] + du * bv.w;
        }
    }
    float4* pp = (float4*)(P + ((size_t)(b * NC + c) * ED + e) * NST);
    pp[0] = make_float4(h[0], h[1], h[2], h[3]);
    pp[1] = make_float4(h[4], h[5], h[6], h[7]);
    pp[2] = make_float4(h[8], h[9], h[10], h[11]);
    pp[3] = make_float4(h[12], h[13], h[14], h[15]);
    S[(size_t)(b * NC + c) * ED + e] = s;
}

__global__ __launch_bounds__(256) void k_scan2(float* __restrict__ P,
                                               const float* __restrict__ S,
                                               const float* __restrict__ A_log) {
    int i = blockIdx.x * 256 + threadIdx.x;
    int n = i & 15;
    int e = (i >> 4) & (ED - 1);
    int b = i >> 14;
    float Ac = -__expf(A_log[(size_t)e * NST + n]);
    float hin = 0.f;
    for (int c = 0; c < NC; ++c) {
        size_t base = (size_t)(b * NC + c) * ED + e;
        float p = P[base * NST + n];
        float s = S[base];
        P[base * NST + n] = hin;
        hin = __expf(Ac * s) * hin + p;
    }
}

__global__ __launch_bounds__(256) void k_scan3(const ushort_t* __restrict__ dyh,
                                               const ushort_t* __restrict__ u,
                                               const float* __restrict__ xdb,
                                               const ushort_t* __restrict__ xzb,
                                               const float* __restrict__ A_log,
                                               const float* __restrict__ Dskip,
                                               const float* __restrict__ P,
                                               ushort_t* __restrict__ yb) {
    int tid = threadIdx.x;
    int e = ((blockIdx.x & 3) << 8) + tid;
    int c = (blockIdx.x >> 2) & (NC - 1);
    int b = blockIdx.x >> 8;
    float Ac[16], h[16];
    const float4* ap = (const float4*)(A_log + (size_t)e * NST);
    #pragma unroll
    for (int q = 0; q < 4; ++q) {
        float4 a = ap[q];
        Ac[q * 4 + 0] = -__expf(a.x); Ac[q * 4 + 1] = -__expf(a.y);
        Ac[q * 4 + 2] = -__expf(a.z); Ac[q * 4 + 3] = -__expf(a.w);
    }
    const float4* pp = (const float4*)(P + ((size_t)(b * NC + c) * ED + e) * NST);
    #pragma unroll
    for (int q = 0; q < 4; ++q) {
        float4 hv = pp[q];
        h[q * 4 + 0] = hv.x; h[q * 4 + 1] = hv.y;
        h[q * 4 + 2] = hv.z; h[q * 4 + 3] = hv.w;
    }
    float Dk = Dskip[e];
    const ushort_t* dp = dyh + ((size_t)b * LL + c * CS) * ED + e;
    const ushort_t* up = u + ((size_t)b * LL + c * CS) * ED + e;
    const float* xp = xdb + ((size_t)b * LL + c * CS) * XDBC;
    const ushort_t* zp = xzb + ((size_t)b * LL + c * CS) * 2048 + 1024 + e;
    ushort_t* yp = yb + ((size_t)b * LL + c * CS) * ED + e;
    for (int tt = 0; tt < CS; ++tt) {
        float dv = h2f(dp[(size_t)tt * ED]);
        float uv = b2f(up[(size_t)tt * ED]);
        float zv = b2f(zp[(size_t)tt * 2048]);
        float du = dv * uv;
        const float4* bp = (const float4*)(xp + tt * XDBC + DTR);
        const float4* cp = (const float4*)(xp + tt * XDBC + DTR + NST);
        float y = 0.f;
        #pragma unroll
        for (int q = 0; q < 4; ++q) {
            float4 bv = bp[q];
            float4 cv = cp[q];
            h[q * 4 + 0] = __expf(dv * Ac[q * 4 + 0]) * h[q * 4 + 0] + du * bv.x;
            h[q * 4 + 1] = __expf(dv * Ac[q * 4 + 1]) * h[q * 4 + 1] + du * bv.y;
            h[q * 4 + 2] = __expf(dv * Ac[q * 4 + 2]) * h[q * 4 + 2] + du * bv.z;
            h[q * 4 + 3] = __expf(dv * Ac[q * 4 + 3]) * h[q * 4 + 3] + du * bv.w;
            y += h[q * 4 + 0] * cv.x + h[q * 4 + 1] * cv.y +
                 h[q * 4 + 2] * cv.z + h[q * 4 + 3] * cv.w;
        }
        yp[(size_t)tt * ED] = f2b((y + Dk * uv) * silu_f(zv));
    }
}

extern "C" void kernel_launch(void* const* d_in, const int* in_sizes, int n_in,
                              void* d_out, int out_size, void* d_ws, size_t ws_size,
                              hipStream_t stream) {
    const float* x     = (const float*)d_in[0];
    const float* embW  = (const float*)d_in[1];
    const float* embB  = (const float*)d_in[2];
    const float* normw = (const float*)d_in[3];
    const float* ipW   = (const float*)d_in[4];
    const float* cW    = (const float*)d_in[5];
    const float* cb    = (const float*)d_in[6];
    const float* xpW   = (const float*)d_in[7];
    const float* dtW   = (const float*)d_in[8];
    const float* dtb   = (const float*)d_in[9];
    const float* Alog  = (const float*)d_in[10];
    const float* Dsk   = (const float*)d_in[11];
    const float* opW   = (const float*)d_in[12];
    const float* normfw= (const float*)d_in[13];
    float* out = (float*)d_out;

    // ws: h 8MB | xzb 16 | ub 8 | xdb 1 | P 16 | S 1 | wip 4 | wop 2 | yb 8 = 64MB
    float* ws  = (float*)d_ws;
    float* h   = ws;
    ushort_t* xzb = (ushort_t*)(h + (size_t)BL * DM);
    ushort_t* ub  = xzb + (size_t)BL * 2 * ED;
    float* xdb = (float*)(ub + (size_t)BL * ED);
    float* P   = xdb + (size_t)BL * XDBC;
    float* S   = P + (size_t)BB * NC * ED * NST;
    ushort_t* wip = (ushort_t*)(S + (size_t)BB * NC * ED);
    ushort_t* wop = wip + (size_t)2 * 2 * ED * DM;
    ushort_t* yb  = wop + (size_t)2 * DM * ED;
    ushort_t* hnb = (ushort_t*)d_out;   // bf16 rmsnorm scratch (d_out reuse)
    ushort_t* dyh = (ushort_t*)d_out;   // fp16 delta (later phase, same mem)

    int nEmb = BL * DM;
    int n1 = 2 * 2 * ED * DM / 4, n2 = 2 * DM * ED / 4;
    k_init<<<(nEmb + n1 + n2 + 255) / 256, 256, 0, stream>>>(
        x, embW, embB, h, ipW, opW, wip, wop, nEmb, n1, n2);

    for (int l = 0; l < 2; ++l) {
        const float* Al = Alog + (size_t)l * ED * NST;
        k_rmsnorm<1><<<BL, 256, 0, stream>>>(h, normw + (size_t)l * DM, hnb);
        k_bgemm<0, 1, 128><<<dim3(2 * ED / 128, BL / 128), 256, 0, stream>>>(
            hnb, wip + (size_t)l * 2 * ED * DM, nullptr, xzb, BL, 2 * ED, DM, DM, 2 * ED);
        k_mid<<<BL / MT, 512, 0, stream>>>(
            xzb, cW + (size_t)l * ED * 4, cb + (size_t)l * ED,
            xpW + (size_t)l * XDBC * ED, dtW + (size_t)l * ED * DTR,
            dtb + (size_t)l * ED, ub, xdb, dyh);
        k_scan1<<<BB * NC * (ED / 256), 256, 0, stream>>>(dyh, ub, xdb, Al, P, S);
        k_scan2<<<BB * ED * NST / 256, 256, 0, stream>>>(P, S, Al);
        k_scan3<<<BB * NC * (ED / 256), 256, 0, stream>>>(
            dyh, ub, xdb, xzb, Al, Dsk + (size_t)l * ED, P, yb);
        k_bgemm<1, 0, 64><<<dim3(DM / 64, BL / 128), 256, 0, stream>>>(
            yb, wop + (size_t)l * DM * ED, h, h, BL, DM, ED, ED, DM);
    }
    k_rmsnorm<0><<<BL, 256, 0, stream>>>(h, normfw, out);
}

// Round 14
// 273.886 us; speedup vs baseline: 1.1114x; 1.1114x over previous
//
#include <hip/hip_runtime.h>
#include <math.h>
#include <stddef.h>

#define BB 4
#define LL 1024
#define DM 512
#define ED 1024
#define NST 16
#define DTR 32
#define XDBC 64
#define BL (BB*LL)   // 4096
#define CS 16        // scan chunk length
#define NC 64        // chunks per sequence (LL/CS)
#define XKS 16       // x_proj K-slices
#define XPAD 68      // x_proj LDS stride (floats)
#define DPAD 132     // k_delta LDS stride (floats)

typedef __attribute__((ext_vector_type(8))) short bf16x8;
typedef __attribute__((ext_vector_type(4))) float f32x4;
typedef unsigned short ushort_t;

__device__ __forceinline__ float silu_f(float x) { return x / (1.f + __expf(-x)); }

__device__ __forceinline__ ushort_t f2b(float f) {
    unsigned int u = __float_as_uint(f);
    unsigned int r = (u + 0x7FFFu + ((u >> 16) & 1u)) >> 16;
    return (ushort_t)r;
}
__device__ __forceinline__ float b2f(ushort_t v) {
    return __uint_as_float(((unsigned int)v) << 16);
}
__device__ __forceinline__ ushort_t f2h(float f) {
    _Float16 h = (_Float16)f;
    return *(ushort_t*)&h;
}
__device__ __forceinline__ float h2f(ushort_t v) {
    _Float16 h = *(_Float16*)&v;
    return (float)h;
}

__device__ __forceinline__ void gload16(const ushort_t* g, ushort_t* l) {
    __builtin_amdgcn_global_load_lds(
        (const __attribute__((address_space(1))) unsigned int*)g,
        (__attribute__((address_space(3))) unsigned int*)l, 16, 0, 0);
}

// ---------------- init: embedding + both weight cvt in one dispatch
__global__ void k_init(const float* __restrict__ x, const float* __restrict__ embW,
                       const float* __restrict__ embB, float* __restrict__ h,
                       const float* __restrict__ ipW, const float* __restrict__ opW,
                       ushort_t* __restrict__ wip, ushort_t* __restrict__ wop,
                       int nEmb, int n1, int n2) {
    int i = blockIdx.x * 256 + threadIdx.x;
    if (i < nEmb) {
        int d = i % DM, r = i / DM;
        h[i] = x[r * 2 + 0] * embW[d * 2 + 0] + x[r * 2 + 1] * embW[d * 2 + 1] + embB[d];
        return;
    }
    i -= nEmb;
    const float* src; ushort_t* dst; int q;
    if (i < n1) { src = ipW; dst = wip; q = i; }
    else if (i < n1 + n2) { src = opW; dst = wop; q = i - n1; }
    else return;
    float4 v = *(const float4*)(src + (size_t)q * 4);
    ushort_t o[4] = {f2b(v.x), f2b(v.y), f2b(v.z), f2b(v.w)};
    *(uint2*)(dst + (size_t)q * 4) = *(uint2*)o;
}

// ---------------- rmsnorm over rows of 512
template <int BF16OUT>
__global__ __launch_bounds__(256) void k_rmsnorm(const float* __restrict__ in,
                                                 const float* __restrict__ w,
                                                 void* __restrict__ outp) {
    int m = blockIdx.x;
    int tid = threadIdx.x;
    const float* row = in + (size_t)m * DM;
    float2 v = *(const float2*)(row + tid * 2);
    float ss = v.x * v.x + v.y * v.y;
    #pragma unroll
    for (int o = 32; o > 0; o >>= 1) ss += __shfl_down(ss, o, 64);
    __shared__ float red[4];
    int wid = tid >> 6;
    if ((tid & 63) == 0) red[wid] = ss;
    __syncthreads();
    float tot = red[0] + red[1] + red[2] + red[3];
    float rs = rsqrtf(tot * (1.f / DM) + 1e-5f);
    float2 wv = *(const float2*)(w + tid * 2);
    float ox = v.x * rs * wv.x;
    float oy = v.y * rs * wv.y;
    if (BF16OUT) {
        ushort_t o[2] = {f2b(ox), f2b(oy)};
        *(unsigned int*)((ushort_t*)outp + (size_t)m * DM + tid * 2) = *(unsigned int*)o;
    } else {
        *(float2*)((float*)outp + (size_t)m * DM + tid * 2) = make_float2(ox, oy);
    }
}

// ---------------- bf16 MFMA GEMM (round-12 structure)
template <int ADDRES, int BF16OUT, int NT>
__global__ __launch_bounds__(256) void k_bgemm(const ushort_t* __restrict__ A,
                                               const ushort_t* __restrict__ W,
                                               const float* __restrict__ Res,
                                               void* __restrict__ C,
                                               int M, int N, int K, int lda, int ldc) {
    __shared__ ushort_t As[128 * 32];
    __shared__ ushort_t Bs[NT * 32];
    constexpr int NFJ = NT / 32;
    int tid = threadIdx.x;
    int bm = blockIdx.y * 128, bn = blockIdx.x * NT;
    int wave = tid >> 6, lane = tid & 63;
    int wr = wave >> 1, wc = wave & 1;
    int lr = lane & 15;
    int kc = lane >> 4;
    f32x4 acc[4][NFJ];
    #pragma unroll
    for (int i = 0; i < 4; ++i)
        #pragma unroll
        for (int j = 0; j < NFJ; ++j) acc[i][j] = (f32x4){0.f, 0.f, 0.f, 0.f};

    for (int k0 = 0; k0 < K; k0 += 32) {
        __syncthreads();
        #pragma unroll
        for (int ii = 0; ii < 2; ++ii) {
            int g = wave * 128 + ii * 64 + lane;
            int row = g >> 2;
            int c = (g & 3) ^ ((g >> 3) & 3);
            gload16(A + (size_t)(bm + row) * lda + k0 + c * 8,
                    As + (size_t)(wave * 128 + ii * 64) * 8);
        }
        #pragma unroll
        for (int ii = 0; ii < NFJ / 2; ++ii) {
            int g = wave * (NFJ / 2) * 64 + ii * 64 + lane;
            int row = g >> 2;
            int c = (g & 3) ^ ((g >> 3) & 3);
            gload16(W + (size_t)(bn + row) * K + k0 + c * 8,
                    Bs + (size_t)(wave * (NFJ / 2) * 64 + ii * 64) * 8);
        }
        __syncthreads();
        bf16x8 af[4], bfr[NFJ];
        #pragma unroll
        for (int i = 0; i < 4; ++i) {
            int ra = wr * 64 + i * 16 + lr;
            int ca = kc ^ ((ra >> 1) & 3);
            af[i] = *(const bf16x8*)(As + ra * 32 + ca * 8);
        }
        #pragma unroll
        for (int j = 0; j < NFJ; ++j) {
            int rb = wc * (NT / 2) + j * 16 + lr;
            int cb = kc ^ ((rb >> 1) & 3);
            bfr[j] = *(const bf16x8*)(Bs + rb * 32 + cb * 8);
        }
        #pragma unroll
        for (int i = 0; i < 4; ++i)
            #pragma unroll
            for (int j = 0; j < NFJ; ++j)
                acc[i][j] = __builtin_amdgcn_mfma_f32_16x16x32_bf16(af[i], bfr[j], acc[i][j], 0, 0, 0);
    }
    int crow0 = bm + wr * 64 + (lane >> 4) * 4;
    #pragma unroll
    for (int i = 0; i < 4; ++i)
        #pragma unroll
        for (int j = 0; j < NFJ; ++j)
            #pragma unroll
            for (int r = 0; r < 4; ++r) {
                size_t off = (size_t)(crow0 + i * 16 + r) * ldc + bn + wc * (NT / 2) + j * 16 + lr;
                float v = acc[i][j][r];
                if (ADDRES) v += Res[off];
                if (BF16OUT) ((ushort_t*)C)[off] = f2b(v);
                else         ((float*)C)[off] = v;
            }
}

// ---------------- fused conv+silu -> x_proj split-K partial
// Block (ks, bm/64): conv for its 64-row x 64-e tile directly into LDS As
// (the tile xproj would stage anyway), write ub global, then 64x64 GEMM
// over this K=64 e-slice -> Pp. Single barrier, same as round-12 k_xproj.
__global__ __launch_bounds__(256) void k_cxp(const ushort_t* __restrict__ xzb,
                                             const float* __restrict__ cw,
                                             const float* __restrict__ cb,
                                             const float* __restrict__ xpW,
                                             ushort_t* __restrict__ ub,
                                             float* __restrict__ Pp) {
    __shared__ float As[64][XPAD];   // [e-within-slice][row]
    __shared__ float Ws[64][XPAD];   // [e-within-slice][n]
    int tid = threadIdx.x;
    int ks = blockIdx.x;
    int bm = blockIdx.y * 64;
    int ec0 = ks * 64;

    // conv phase: 4 rows x 4 e per thread
    {
        int r0 = (tid >> 4) * 4;
        int e4 = (tid & 15) * 4;
        int e = ec0 + e4;
        float cw4[4][4], cb4[4];
        #pragma unroll
        for (int j = 0; j < 4; ++j) {
            float4 w = *(const float4*)(cw + (size_t)(e + j) * 4);
            cw4[j][0] = w.x; cw4[j][1] = w.y; cw4[j][2] = w.z; cw4[j][3] = w.w;
        }
        float4 cbv = *(const float4*)(cb + e);
        cb4[0] = cbv.x; cb4[1] = cbv.y; cb4[2] = cbv.z; cb4[3] = cbv.w;
        #pragma unroll
        for (int i = 0; i < 4; ++i) {
            int row = bm + r0 + i;
            int tloc = row & (LL - 1);
            const ushort_t* xrow = xzb + (size_t)row * 2048 + e;
            uint2 z2 = make_uint2(0, 0);
            uint2 v3 = *(const uint2*)xrow;
            uint2 v2 = (tloc >= 1) ? *(const uint2*)(xrow - 2048) : z2;
            uint2 v1 = (tloc >= 2) ? *(const uint2*)(xrow - 4096) : z2;
            uint2 v0 = (tloc >= 3) ? *(const uint2*)(xrow - 6144) : z2;
            const ushort_t* p0 = (const ushort_t*)&v0;
            const ushort_t* p1 = (const ushort_t*)&v1;
            const ushort_t* p2 = (const ushort_t*)&v2;
            const ushort_t* p3 = (const ushort_t*)&v3;
            ushort_t ures[4];
            #pragma unroll
            for (int j = 0; j < 4; ++j) {
                float a = cb4[j] + b2f(p0[j]) * cw4[j][0] + b2f(p1[j]) * cw4[j][1]
                                 + b2f(p2[j]) * cw4[j][2] + b2f(p3[j]) * cw4[j][3];
                float uu = silu_f(a);
                As[e4 + j][r0 + i] = uu;
                ures[j] = f2b(uu);
            }
            *(uint2*)(ub + (size_t)row * ED + e) = *(uint2*)ures;
        }
    }
    // Ws staging (independent of As)
    {
        int r = tid >> 2;
        int kc = (tid & 3) * 16;
        const float4* wp = (const float4*)(xpW + (size_t)r * ED + ec0 + kc);
        #pragma unroll
        for (int i = 0; i < 4; ++i) {
            float4 wv = wp[i];
            Ws[kc + i * 4 + 0][r] = wv.x; Ws[kc + i * 4 + 1][r] = wv.y;
            Ws[kc + i * 4 + 2][r] = wv.z; Ws[kc + i * 4 + 3][r] = wv.w;
        }
    }
    __syncthreads();
    int tm = (tid >> 4) * 4;
    int tn = (tid & 15) * 4;
    float acc[4][4] = {};
    #pragma unroll 4
    for (int k = 0; k < 64; ++k) {
        float4 a = *(const float4*)&As[k][tm];
        float4 b = *(const float4*)&Ws[k][tn];
        acc[0][0] += a.x * b.x; acc[0][1] += a.x * b.y; acc[0][2] += a.x * b.z; acc[0][3] += a.x * b.w;
        acc[1][0] += a.y * b.x; acc[1][1] += a.y * b.y; acc[1][2] += a.y * b.z; acc[1][3] += a.y * b.w;
        acc[2][0] += a.z * b.x; acc[2][1] += a.z * b.y; acc[2][2] += a.z * b.z; acc[2][3] += a.z * b.w;
        acc[3][0] += a.w * b.x; acc[3][1] += a.w * b.y; acc[3][2] += a.w * b.z; acc[3][3] += a.w * b.w;
    }
    float* pp = Pp + (size_t)ks * BL * XDBC;
    #pragma unroll
    for (int i = 0; i < 4; ++i)
        *(float4*)(pp + (size_t)(bm + tm + i) * XDBC + tn) =
            make_float4(acc[i][0], acc[i][1], acc[i][2], acc[i][3]);
}

// reduce 16 K-slice partials -> xdb
__global__ void k_xred(const float* __restrict__ Pp, float* __restrict__ xdb) {
    int i = blockIdx.x * 256 + threadIdx.x;
    float4 s = make_float4(0.f, 0.f, 0.f, 0.f);
    #pragma unroll
    for (int sl = 0; sl < XKS; ++sl) {
        float4 v = *(const float4*)(Pp + (size_t)sl * BL * XDBC + (size_t)i * 4);
        s.x += v.x; s.y += v.y; s.z += v.z; s.w += v.w;
    }
    *(float4*)(xdb + (size_t)i * 4) = s;
}

// ---------------- delta = softplus(dt @ dtW^T + dtb), tiled; fp16 output
__global__ __launch_bounds__(256) void k_delta(const float* __restrict__ xdb,
                                               const float* __restrict__ dtW,
                                               const float* __restrict__ dtb,
                                               ushort_t* __restrict__ dyh) {
    __shared__ float Dt[32][DPAD];
    __shared__ float Wt[32][DPAD];
    int tid = threadIdx.x;
    int bm = blockIdx.y * 128;
    int bn = blockIdx.x * 128;
    int r = tid >> 1;
    int hh = (tid & 1) * 16;
    const float4* dp = (const float4*)(xdb + (size_t)(bm + r) * XDBC + hh);
    const float4* wp = (const float4*)(dtW + (size_t)(bn + r) * 32 + hh);
    #pragma unroll
    for (int i = 0; i < 4; ++i) {
        float4 v = dp[i];
        Dt[hh + i * 4 + 0][r] = v.x; Dt[hh + i * 4 + 1][r] = v.y;
        Dt[hh + i * 4 + 2][r] = v.z; Dt[hh + i * 4 + 3][r] = v.w;
        float4 w = wp[i];
        Wt[hh + i * 4 + 0][r] = w.x; Wt[hh + i * 4 + 1][r] = w.y;
        Wt[hh + i * 4 + 2][r] = w.z; Wt[hh + i * 4 + 3][r] = w.w;
    }
    __syncthreads();
    int tm = (tid >> 4) * 8;
    int tn = (tid & 15) * 8;
    float acc[8][8] = {};
    #pragma unroll 8
    for (int k = 0; k < 32; ++k) {
        float4 a0 = *(const float4*)&Dt[k][tm];
        float4 a1 = *(const float4*)&Dt[k][tm + 4];
        float4 b0 = *(const float4*)&Wt[k][tn];
        float4 b1 = *(const float4*)&Wt[k][tn + 4];
        float a[8] = {a0.x, a0.y, a0.z, a0.w, a1.x, a1.y, a1.z, a1.w};
        float b[8] = {b0.x, b0.y, b0.z, b0.w, b1.x, b1.y, b1.z, b1.w};
        #pragma unroll
        for (int i = 0; i < 8; ++i)
            #pragma unroll
            for (int j = 0; j < 8; ++j) acc[i][j] += a[i] * b[j];
    }
    float4 t0 = *(const float4*)(dtb + bn + tn);
    float4 t1 = *(const float4*)(dtb + bn + tn + 4);
    float bias[8] = {t0.x, t0.y, t0.z, t0.w, t1.x, t1.y, t1.z, t1.w};
    #pragma unroll
    for (int i = 0; i < 8; ++i) {
        ushort_t o16[8];
        #pragma unroll
        for (int j = 0; j < 8; ++j) {
            float v = acc[i][j] + bias[j];
            v = (v > 20.f) ? v : __logf(1.f + __expf(v));
            o16[j] = f2h(v);
        }
        size_t off = (size_t)(bm + tm + i) * ED + bn + tn;
        *(uint4*)(dyh + off) = *(uint4*)o16;
    }
}

// ================ chunked selective scan (CS=16, NC=64) ================
__global__ __launch_bounds__(256) void k_scan1(const ushort_t* __restrict__ dyh,
                                               const ushort_t* __restrict__ u,
                                               const float* __restrict__ xdb,
                                               const float* __restrict__ A_log,
                                               float* __restrict__ P,
                                               float* __restrict__ S) {
    int tid = threadIdx.x;
    int e = ((blockIdx.x & 3) << 8) + tid;
    int c = (blockIdx.x >> 2) & (NC - 1);
    int b = blockIdx.x >> 8;
    float Ac[16];
    const float4* ap = (const float4*)(A_log + (size_t)e * NST);
    #pragma unroll
    for (int q = 0; q < 4; ++q) {
        float4 a = ap[q];
        Ac[q * 4 + 0] = -__expf(a.x); Ac[q * 4 + 1] = -__expf(a.y);
        Ac[q * 4 + 2] = -__expf(a.z); Ac[q * 4 + 3] = -__expf(a.w);
    }
    float h[16] = {};
    float s = 0.f;
    const ushort_t* dp = dyh + ((size_t)b * LL + c * CS) * ED + e;
    const ushort_t* up = u + ((size_t)b * LL + c * CS) * ED + e;
    const float* xp = xdb + ((size_t)b * LL + c * CS) * XDBC;
    for (int tt = 0; tt < CS; ++tt) {
        float dv = h2f(dp[(size_t)tt * ED]);
        float uv = b2f(up[(size_t)tt * ED]);
        s += dv;
        float du = dv * uv;
        const float4* bp = (const float4*)(xp + tt * XDBC + DTR);
        #pragma unroll
        for (int q = 0; q < 4; ++q) {
            float4 bv = bp[q];
            h[q * 4 + 0] = __expf(dv * Ac[q * 4 + 0]) * h[q * 4 + 0] + du * bv.x;
            h[q * 4 + 1] = __expf(dv * Ac[q * 4 + 1]) * h[q * 4 + 1] + du * bv.y;
            h[q * 4 + 2] = __expf(dv * Ac[q * 4 + 2]) * h[q * 4 + 2] + du * bv.z;
            h[q * 4 + 3] = __expf(dv * Ac[q * 4 + 3]) * h[q * 4 + 3] + du * bv.w;
        }
    }
    float4* pp = (float4*)(P + ((size_t)(b * NC + c) * ED + e) * NST);
    pp[0] = make_float4(h[0], h[1], h[2], h[3]);
    pp[1] = make_float4(h[4], h[5], h[6], h[7]);
    pp[2] = make_float4(h[8], h[9], h[10], h[11]);
    pp[3] = make_float4(h[12], h[13], h[14], h[15]);
    S[(size_t)(b * NC + c) * ED + e] = s;
}

__global__ __launch_bounds__(256) void k_scan2(float* __restrict__ P,
                                               const float* __restrict__ S,
                                               const float* __restrict__ A_log) {
    int i = blockIdx.x * 256 + threadIdx.x;
    int n = i & 15;
    int e = (i >> 4) & (ED - 1);
    int b = i >> 14;
    float Ac = -__expf(A_log[(size_t)e * NST + n]);
    float hin = 0.f;
    for (int c = 0; c < NC; ++c) {
        size_t base = (size_t)(b * NC + c) * ED + e;
        float p = P[base * NST + n];
        float s = S[base];
        P[base * NST + n] = hin;
        hin = __expf(Ac * s) * hin + p;
    }
}

__global__ __launch_bounds__(256) void k_scan3(const ushort_t* __restrict__ dyh,
                                               const ushort_t* __restrict__ u,
                                               const float* __restrict__ xdb,
                                               const ushort_t* __restrict__ xzb,
                                               const float* __restrict__ A_log,
                                               const float* __restrict__ Dskip,
                                               const float* __restrict__ P,
                                               ushort_t* __restrict__ yb) {
    int tid = threadIdx.x;
    int e = ((blockIdx.x & 3) << 8) + tid;
    int c = (blockIdx.x >> 2) & (NC - 1);
    int b = blockIdx.x >> 8;
    float Ac[16], h[16];
    const float4* ap = (const float4*)(A_log + (size_t)e * NST);
    #pragma unroll
    for (int q = 0; q < 4; ++q) {
        float4 a = ap[q];
        Ac[q * 4 + 0] = -__expf(a.x); Ac[q * 4 + 1] = -__expf(a.y);
        Ac[q * 4 + 2] = -__expf(a.z); Ac[q * 4 + 3] = -__expf(a.w);
    }
    const float4* pp = (const float4*)(P + ((size_t)(b * NC + c) * ED + e) * NST);
    #pragma unroll
    for (int q = 0; q < 4; ++q) {
        float4 hv = pp[q];
        h[q * 4 + 0] = hv.x; h[q * 4 + 1] = hv.y;
        h[q * 4 + 2] = hv.z; h[q * 4 + 3] = hv.w;
    }
    float Dk = Dskip[e];
    const ushort_t* dp = dyh + ((size_t)b * LL + c * CS) * ED + e;
    const ushort_t* up = u + ((size_t)b * LL + c * CS) * ED + e;
    const float* xp = xdb + ((size_t)b * LL + c * CS) * XDBC;
    const ushort_t* zp = xzb + ((size_t)b * LL + c * CS) * 2048 + 1024 + e;
    ushort_t* yp = yb + ((size_t)b * LL + c * CS) * ED + e;
    for (int tt = 0; tt < CS; ++tt) {
        float dv = h2f(dp[(size_t)tt * ED]);
        float uv = b2f(up[(size_t)tt * ED]);
        float zv = b2f(zp[(size_t)tt * 2048]);
        float du = dv * uv;
        const float4* bp = (const float4*)(xp + tt * XDBC + DTR);
        const float4* cp = (const float4*)(xp + tt * XDBC + DTR + NST);
        float y = 0.f;
        #pragma unroll
        for (int q = 0; q < 4; ++q) {
            float4 bv = bp[q];
            float4 cv = cp[q];
            h[q * 4 + 0] = __expf(dv * Ac[q * 4 + 0]) * h[q * 4 + 0] + du * bv.x;
            h[q * 4 + 1] = __expf(dv * Ac[q * 4 + 1]) * h[q * 4 + 1] + du * bv.y;
            h[q * 4 + 2] = __expf(dv * Ac[q * 4 + 2]) * h[q * 4 + 2] + du * bv.z;
            h[q * 4 + 3] = __expf(dv * Ac[q * 4 + 3]) * h[q * 4 + 3] + du * bv.w;
            y += h[q * 4 + 0] * cv.x + h[q * 4 + 1] * cv.y +
                 h[q * 4 + 2] * cv.z + h[q * 4 + 3] * cv.w;
        }
        yp[(size_t)tt * ED] = f2b((y + Dk * uv) * silu_f(zv));
    }
}

extern "C" void kernel_launch(void* const* d_in, const int* in_sizes, int n_in,
                              void* d_out, int out_size, void* d_ws, size_t ws_size,
                              hipStream_t stream) {
    const float* x     = (const float*)d_in[0];
    const float* embW  = (const float*)d_in[1];
    const float* embB  = (const float*)d_in[2];
    const float* normw = (const float*)d_in[3];
    const float* ipW   = (const float*)d_in[4];
    const float* cW    = (const float*)d_in[5];
    const float* cb    = (const float*)d_in[6];
    const float* xpW   = (const float*)d_in[7];
    const float* dtW   = (const float*)d_in[8];
    const float* dtb   = (const float*)d_in[9];
    const float* Alog  = (const float*)d_in[10];
    const float* Dsk   = (const float*)d_in[11];
    const float* opW   = (const float*)d_in[12];
    const float* normfw= (const float*)d_in[13];
    float* out = (float*)d_out;

    // ws: h 8MB | xzb 16 | ub 8 | xdb 1 | Pp/P 16 (aliased, disjoint phases)
    //     | S 1 | wip 4 | wop 2 | yb 8  = 64 MB
    float* ws  = (float*)d_ws;
    float* h   = ws;
    ushort_t* xzb = (ushort_t*)(h + (size_t)BL * DM);
    ushort_t* ub  = xzb + (size_t)BL * 2 * ED;
    float* xdb = (float*)(ub + (size_t)BL * ED);
    float* Pp  = xdb + (size_t)BL * XDBC;
    float* S   = Pp + (size_t)XKS * BL * XDBC;
    ushort_t* wip = (ushort_t*)(S + (size_t)BB * NC * ED);
    ushort_t* wop = wip + (size_t)2 * 2 * ED * DM;
    ushort_t* yb  = wop + (size_t)2 * DM * ED;
    float* P      = Pp;                 // chunk-state buffer aliases Pp
    ushort_t* hnb = (ushort_t*)d_out;   // bf16 rmsnorm scratch
    ushort_t* dyh = (ushort_t*)d_out;   // fp16 delta (later phase, same mem)

    int nEmb = BL * DM;
    int n1 = 2 * 2 * ED * DM / 4, n2 = 2 * DM * ED / 4;
    k_init<<<(nEmb + n1 + n2 + 255) / 256, 256, 0, stream>>>(
        x, embW, embB, h, ipW, opW, wip, wop, nEmb, n1, n2);

    for (int l = 0; l < 2; ++l) {
        const float* Al = Alog + (size_t)l * ED * NST;
        k_rmsnorm<1><<<BL, 256, 0, stream>>>(h, normw + (size_t)l * DM, hnb);
        k_bgemm<0, 1, 128><<<dim3(2 * ED / 128, BL / 128), 256, 0, stream>>>(
            hnb, wip + (size_t)l * 2 * ED * DM, nullptr, xzb, BL, 2 * ED, DM, DM, 2 * ED);
        k_cxp<<<dim3(XKS, BL / 64), 256, 0, stream>>>(
            xzb, cW + (size_t)l * ED * 4, cb + (size_t)l * ED,
            xpW + (size_t)l * XDBC * ED, ub, Pp);
        k_xred<<<BL * XDBC / 4 / 256, 256, 0, stream>>>(Pp, xdb);
        k_delta<<<dim3(ED / 128, BL / 128), 256, 0, stream>>>(
            xdb, dtW + (size_t)l * ED * DTR, dtb + (size_t)l * ED, dyh);
        k_scan1<<<BB * NC * (ED / 256), 256, 0, stream>>>(dyh, ub, xdb, Al, P, S);
        k_scan2<<<BB * ED * NST / 256, 256, 0, stream>>>(P, S, Al);
        k_scan3<<<BB * NC * (ED / 256), 256, 0, stream>>>(
            dyh, ub, xdb, xzb, Al, Dsk + (size_t)l * ED, P, yb);
        k_bgemm<1, 0, 64><<<dim3(DM / 64, BL / 128), 256, 0, stream>>>(
            yb, wop + (size_t)l * DM * ED, h, h, BL, DM, ED, ED, DM);
    }
    k_rmsnorm<0><<<BL, 256, 0, stream>>>(h, normfw, out);
}